// Round 7
// baseline (159.263 us; speedup 1.0000x reference)
//
#include <hip/hip_runtime.h>
#include <math.h>

// DSHW — R7: lane-coalesced vm in the scan loop.
// R6 left ~400 cyc/step with VALUBusy~9% (active CUs): residual pacer theory =
// 3 address-divergent vm ops/step (strided y load + 2 strided f32 stores,
// 32 cache lines per op). R7: y pre-transposed to [step][series] (1 coalesced
// f32 load/step), yhat stored f64 to [step][series] (1 coalesced 8B store/
// step), yh/e/fcast/Ic/wc emitted by a parallel finish kernel with textually
// identical f64 expressions -> bit-identical outputs to R6.

#define P1c   24
#define P2c   168
#define NSTEP 512
#define BSc   64
#define NFc   16
#define MAXH  336
#define NT    32
#define NSERIES 1024

#define OFF_FC   0
#define OFF_YH   (BSc * MAXH * NFc)
#define OFF_E    (OFF_YH + BSc * NSTEP * NFc)
#define OFF_IC   (OFF_E  + BSc * NSTEP * NFc)
#define OFF_WC   (OFF_IC + BSc * P1c * NFc)
#define OFF_T    (OFF_WC + BSc * P2c * NFc)
#define OFF_S    (OFF_T  + BSc * NFc)

// ws layout (bytes)
#define WSO_Y    0                                        // f32 [NSTEP][NSERIES]
#define WSO_YH   (WSO_Y  + (size_t)NSTEP * NSERIES * 4)   // f64 [NSTEP][NSERIES]
#define WSO_ST   (WSO_YH + (size_t)NSTEP * NSERIES * 8)   // f64 [194][NSERIES]
#define WS_NEED  (WSO_ST + (size_t)194 * NSERIES * 8)

__device__ __forceinline__ double nrcp(double a) {
    double x = __builtin_amdgcn_rcp(a);          // v_rcp_f64, no VCC
    x = fma(fma(-a, x, 1.0), x, x);
    x = fma(fma(-a, x, 1.0), x, x);              // ~1 ulp
    return x;
}

// ---------------------------------------------------------------------------
// Kernel A: y [64][512][16] f32 -> wsy [512][1024] f32  (wsy[n][b*16+f])
// ---------------------------------------------------------------------------
__global__ __launch_bounds__(256)
void dshw_transpose(const float* __restrict__ y, float* __restrict__ wsy)
{
    const int idx = blockIdx.x * 256 + threadIdx.x;      // 0..524287
    const int n   = idx >> 10;
    const int sfi = idx & 1023;
    const int b   = sfi >> 4;
    const int f   = sfi & 15;
    wsy[idx] = y[((size_t)b * NSTEP + n) * NFc + f];
}

// ---------------------------------------------------------------------------
// Kernel B: init + scan. All vm in the loop is lane-coalesced.
// ---------------------------------------------------------------------------
__global__ __launch_bounds__(NT, 1)
void dshw_scan5(const float* __restrict__ wsy,
                const float* __restrict__ alphas,
                const float* __restrict__ betas,
                const float* __restrict__ gammas,
                const float* __restrict__ omegas,
                double* __restrict__ wsyh,
                double* __restrict__ wsst,
                float* __restrict__ out)
{
    __shared__ double sW[P2c][NT];   // wc only — 42 KiB

    const int tid = threadIdx.x;
    const int g   = blockIdx.x * NT + tid;
    const int bb  = g >> 4;
    const int f   = g & 15;

    const double al = 1.0 / (1.0 + exp(-(double)alphas[f]));
    const double be = 1.0 / (1.0 + exp(-(double)betas[f]));
    const double ga = 1.0 / (1.0 + exp(-(double)gammas[f]));
    const double om = 1.0 / (1.0 + exp(-(double)omegas[f]));
    const double one_m_al = 1.0 - al, one_m_be = 1.0 - be;
    const double one_m_ga = 1.0 - ga, one_m_om = 1.0 - om;

    // ---------------- init (coalesced loads; same summation order) ----------
    double Icr[P1c];
    double sum48 = 0.0;
    #pragma unroll
    for (int ph = 0; ph < P1c; ++ph) {
        double v0 = (double)wsy[ph * NSERIES + g];
        double v1 = (double)wsy[(ph + P1c) * NSERIES + g];
        Icr[ph] = 0.5 * (v0 + v1);
        sum48 += v0 + v1;
    }
    const double inv_mean48 = 48.0 * nrcp(sum48);
    #pragma unroll
    for (int ph = 0; ph < P1c; ++ph) Icr[ph] *= inv_mean48;

    double sa = 0.0, sb = 0.0;
    #pragma unroll 8
    for (int i = 0; i < P2c; ++i) {
        double v0 = (double)wsy[i * NSERIES + g];
        double v1 = (double)wsy[(i + P2c) * NSERIES + g];
        sW[i][tid] = 0.5 * (v0 + v1);
        sa += v0; sb += v1;
    }
    const double mean336     = (sa + sb) * (1.0 / 336.0);
    const double inv_mean336 = nrcp(mean336);
    #pragma unroll
    for (int ph = 0; ph < P1c; ++ph) {
        double rI = inv_mean336 * nrcp(Icr[ph]);
        #pragma unroll
        for (int r = 0; r < 7; ++r) {
            const int i = ph + 24 * r;
            sW[i][tid] = sW[i][tid] * rI;
        }
    }

    double tt = 0.5 * ((sa - sb) * (1.0 / (168.0 * 168.0)) +
                       ((double)wsy[(P2c - 1) * NSERIES + g] -
                        (double)wsy[0 * NSERIES + g]) * (1.0 / 168.0));
    double ss = mean336 - 168.5 * tt;

    // ---------------- scan ----------------
    float yfr[24];            // yfr[m%24] holds f32 y_m
    double wring[24], uring[8], iwring[6], snring[3];

    #pragma unroll
    for (int k = 0; k < 12; ++k) yfr[k] = wsy[k * NSERIES + g];
    #pragma unroll
    for (int k = 0; k < 12; ++k) wring[k] = sW[k][tid];
    // B warmup: steps 0..3
    #pragma unroll
    for (int m = 0; m < 4; ++m) {
        double iw  = Icr[m] * wring[m];
        double inv = nrcp(iw);
        iwring[m % 6] = iw;
        uring[m % 8]  = (double)yfr[m] * inv;
    }

    int i2r = 12;   // LDS read phase (s+12) % 168
    int i2w = 0;    // LDS write phase (s-2) % 168

    // ---- group 0 (s0 = 0): D guarded for j < 2 ----
    #pragma unroll
    for (int j = 0; j < 24; ++j) {
        const int s = j;
        // C
        double spt  = ss + tt;
        double yhat = spt * iwring[j % 6];
        double snew = al * uring[j % 8] + one_m_al * spt;
        double tnew = be * (snew - ss) + one_m_be * tt;
        wsyh[(size_t)s * NSERIES + g] = yhat;          // coalesced 8B store
        snring[j % 3] = snew;
        ss = snew; tt = tnew;
        // A
        wring[(j + 12) % 24] = sW[i2r][tid];
        i2r = (i2r + 1 == P2c) ? 0 : i2r + 1;
        yfr[(j + 12) % 24] = wsy[(s + 12) * NSERIES + g];   // coalesced
        // B (step s+4)
        {
            double iw2  = Icr[(j + 4) % 24] * wring[(j + 4) % 24];
            double inv2 = nrcp(iw2);
            iwring[(j + 4) % 6] = iw2;
            uring[(j + 4) % 8]  = (double)yfr[(j + 4) % 24] * inv2;
        }
        // D (step s-2)
        if (j >= 2) {
            double r   = nrcp(snring[(j + 1) % 3]);
            double uDr = uring[(j + 6) % 8] * r;
            double icO = Icr[(j + 22) % 24];
            double wcO = wring[(j + 22) % 24];
            Icr[(j + 22) % 24] = icO * fma(ga, uDr, one_m_ga);
            sW[i2w][tid] = wcO * fma(om, uDr, one_m_om);
            i2w = (i2w + 1 == P2c) ? 0 : i2w + 1;
        }
    }

    // ---- steady groups: s0 = 24..480 ----
    for (int s0 = 24; s0 <= 480; s0 += 24) {
        #pragma unroll
        for (int j = 0; j < 24; ++j) {
            const int s = s0 + j;
            // C
            double spt  = ss + tt;
            double yhat = spt * iwring[j % 6];
            double snew = al * uring[j % 8] + one_m_al * spt;
            double tnew = be * (snew - ss) + one_m_be * tt;
            wsyh[(size_t)s * NSERIES + g] = yhat;      // coalesced 8B store
            snring[j % 3] = snew;
            ss = snew; tt = tnew;
            // A
            wring[(j + 12) % 24] = sW[i2r][tid];
            i2r = (i2r + 1 == P2c) ? 0 : i2r + 1;
            int pidx = s + 12; pidx = (pidx < NSTEP) ? pidx : (NSTEP - 1);
            yfr[(j + 12) % 24] = wsy[pidx * NSERIES + g];   // coalesced
            // B (step s+4)
            {
                double iw2  = Icr[(j + 4) % 24] * wring[(j + 4) % 24];
                double inv2 = nrcp(iw2);
                iwring[(j + 4) % 6] = iw2;
                uring[(j + 4) % 8]  = (double)yfr[(j + 4) % 24] * inv2;
            }
            // D (step s-2)
            {
                double r   = nrcp(snring[(j + 1) % 3]);
                double uDr = uring[(j + 6) % 8] * r;
                double icO = Icr[(j + 22) % 24];
                double wcO = wring[(j + 22) % 24];
                Icr[(j + 22) % 24] = icO * fma(ga, uDr, one_m_ga);
                sW[i2w][tid] = wcO * fma(om, uDr, one_m_om);
                i2w = (i2w + 1 == P2c) ? 0 : i2w + 1;
            }
        }
    }

    // ---- tail: steps 504..511 ----
    #pragma unroll
    for (int j = 0; j < 8; ++j) {
        const int s = 504 + j;
        double spt  = ss + tt;
        double yhat = spt * iwring[j % 6];
        double snew = al * uring[j % 8] + one_m_al * spt;
        double tnew = be * (snew - ss) + one_m_be * tt;
        wsyh[(size_t)s * NSERIES + g] = yhat;
        snring[j % 3] = snew;
        ss = snew; tt = tnew;
        if (j < 4) {   // B for steps 508..511
            double iw2  = Icr[(j + 4) % 24] * wring[(j + 4) % 24];
            double inv2 = nrcp(iw2);
            iwring[(j + 4) % 6] = iw2;
            uring[(j + 4) % 8]  = (double)yfr[(j + 4) % 24] * inv2;
        }
        {   // D for steps 502..509
            double r   = nrcp(snring[(j + 1) % 3]);
            double uDr = uring[(j + 6) % 8] * r;
            double icO = Icr[(j + 22) % 24];
            double wcO = wring[(j + 22) % 24];
            Icr[(j + 22) % 24] = icO * fma(ga, uDr, one_m_ga);
            sW[i2w][tid] = wcO * fma(om, uDr, one_m_om);
            i2w = (i2w + 1 == P2c) ? 0 : i2w + 1;
        }
    }
    // drain D: steps 510, 511
    {
        double r   = nrcp(snring[0]);
        double uDr = uring[6] * r;
        double icO = Icr[6], wcO = wring[6];
        Icr[6] = icO * fma(ga, uDr, one_m_ga);
        sW[i2w][tid] = wcO * fma(om, uDr, one_m_om);
        i2w = (i2w + 1 == P2c) ? 0 : i2w + 1;
    }
    {
        double r   = nrcp(snring[1]);
        double uDr = uring[7] * r;
        double icO = Icr[7], wcO = wring[7];
        Icr[7] = icO * fma(ga, uDr, one_m_ga);
        sW[i2w][tid] = wcO * fma(om, uDr, one_m_om);
    }

    // dump raw f64 state, item-major (coalesced)
    #pragma unroll
    for (int p = 0; p < P1c; ++p)  wsst[(size_t)p * NSERIES + g] = Icr[p];
    #pragma unroll 8
    for (int p = 0; p < P2c; ++p)  wsst[(size_t)(P1c + p) * NSERIES + g] = sW[p][tid];
    wsst[(size_t)192 * NSERIES + g] = ss;
    wsst[(size_t)193 * NSERIES + g] = tt;

    out[OFF_T + bb * NFc + f] = (float)tt;
    out[OFF_S + bb * NFc + f] = (float)ss;
}

// ---------------------------------------------------------------------------
// Kernel C: finish — yh, e, fcast, rolled Ic/wc. 1040 items x 1024 series.
// items: 0..511 yh/e (n), 512..847 fcast (k), 848..871 Ic (j), 872..1039 wc (j)
// ---------------------------------------------------------------------------
__global__ __launch_bounds__(256)
void dshw_finish(const float* __restrict__ wsy,
                 const double* __restrict__ wsyh,
                 const double* __restrict__ wsst,
                 float* __restrict__ out)
{
    const int f      = threadIdx.x & 15;
    const int isub   = threadIdx.x >> 4;
    const int bb     = blockIdx.x & 63;
    const int chunk  = blockIdx.x >> 6;       // 0..64
    const int item   = chunk * 16 + isub;     // 0..1039
    const int series = bb * NFc + f;

    if (item < NSTEP) {
        const int n = item;
        double yh = wsyh[(size_t)n * NSERIES + series];
        double yt = (double)wsy[(size_t)n * NSERIES + series];
        out[OFF_YH + (bb * NSTEP + n) * NFc + f] = (float)yh;
        out[OFF_E  + (bb * NSTEP + n) * NFc + f] = (float)(yt - yh);
    } else if (item < NSTEP + MAXH) {
        const int k = item - NSTEP;
        double cb = wsst[(size_t)((k + 8) % P1c) * NSERIES + series];
        double cc = wsst[(size_t)(P1c + (k + 8) % P2c) * NSERIES + series];
        double ssv = wsst[(size_t)192 * NSERIES + series];
        double ttv = wsst[(size_t)193 * NSERIES + series];
        double ca = ssv + (double)(k + 1) * ttv;
        out[OFF_FC + (bb * MAXH + k) * NFc + f] = (float)(ca * cb * cc);
    } else if (item < NSTEP + MAXH + P1c) {
        const int j = item - (NSTEP + MAXH);
        out[OFF_IC + (bb * P1c + j) * NFc + f] =
            (float)wsst[(size_t)((j + 8) % P1c) * NSERIES + series];
    } else if (item < NSTEP + MAXH + P1c + P2c) {
        const int j = item - (NSTEP + MAXH + P1c);
        out[OFF_WC + (bb * P2c + j) * NFc + f] =
            (float)wsst[(size_t)(P1c + (j + 8) % P2c) * NSERIES + series];
    }
}

// ---------------------------------------------------------------------------
// Fallback (R2 fused kernel, verbatim) — used only if ws is too small.
// ---------------------------------------------------------------------------
__global__ __launch_bounds__(NT, 1)
void dshw_fused(const float* __restrict__ y,
                const float* __restrict__ alphas,
                const float* __restrict__ betas,
                const float* __restrict__ gammas,
                const float* __restrict__ omegas,
                float* __restrict__ out)
{
    __shared__ double sIc[P1c][NT];
    __shared__ double sWc[P2c][NT];

    const int tid = threadIdx.x;
    const int g   = blockIdx.x * NT + tid;
    const int bb  = g >> 4;
    const int f   = g & 15;

    const float* __restrict__ yb = y + (size_t)bb * NSTEP * NFc + f;

    const double al = 1.0 / (1.0 + exp(-(double)alphas[f]));
    const double be = 1.0 / (1.0 + exp(-(double)betas[f]));
    const double ga = 1.0 / (1.0 + exp(-(double)gammas[f]));
    const double om = 1.0 / (1.0 + exp(-(double)omegas[f]));

    double sum48 = 0.0;
    #pragma unroll
    for (int ph = 0; ph < P1c; ++ph) {
        double v0 = (double)yb[ph * NFc];
        double v1 = (double)yb[(ph + P1c) * NFc];
        sIc[ph][tid] = 0.5 * (v0 + v1);
        sum48 += v0 + v1;
    }
    const double inv_mean48 = 48.0 / sum48;
    #pragma unroll
    for (int ph = 0; ph < P1c; ++ph) sIc[ph][tid] *= inv_mean48;

    double sum168a = 0.0, sum168b = 0.0;
    for (int i = 0; i < P2c; ++i) {
        double v0 = (double)yb[i * NFc];
        double v1 = (double)yb[(i + P2c) * NFc];
        sWc[i][tid] = 0.5 * (v0 + v1);
        sum168a += v0;
        sum168b += v1;
    }
    const double mean336 = (sum168a + sum168b) * (1.0 / 336.0);
    for (int i = 0; i < P2c; ++i) {
        sWc[i][tid] = (sWc[i][tid] / mean336) / sIc[i % P1c][tid];
    }

    double tt = 0.5 * ((sum168a - sum168b) * (1.0 / (168.0 * 168.0)) +
                       ((double)yb[(P2c - 1) * NFc] - (double)yb[0]) * (1.0 / 168.0));
    double ss = mean336 - 168.5 * tt;

    float* __restrict__ yh_o = out + OFF_YH + (size_t)bb * NSTEP * NFc + f;
    float* __restrict__ e_o  = out + OFF_E  + (size_t)bb * NSTEP * NFc + f;

    int i1 = 0, i2 = 0;
    int i1p = 2, i2p = 2;

    double Icv0 = sIc[0][tid], Icv1 = sIc[1][tid];
    double wcv0 = sWc[0][tid], wcv1 = sWc[1][tid];
    double yt0 = (double)yb[0 * NFc], yt1 = (double)yb[1 * NFc];
    double yt2 = (double)yb[2 * NFc], yt3 = (double)yb[3 * NFc];

    #pragma unroll 4
    for (int step = 0; step < NSTEP; ++step) {
        double Icv2 = sIc[i1p][tid];
        double wcv2 = sWc[i2p][tid];
        int    pidx = step + 4; pidx = (pidx < NSTEP) ? pidx : (NSTEP - 1);
        double yt4  = (double)yb[pidx * NFc];

        double iw     = Icv0 * wcv0;
        double spt    = ss + tt;
        double yhat   = spt * iw;
        double inv_iw = 1.0 / iw;
        double u      = yt0 * inv_iw;
        double snew   = al * u + (1.0 - al) * spt;
        double tnew   = be * (snew - ss) + (1.0 - be) * tt;
        double q      = yt0 / snew;
        double icn    = ga * (q * (inv_iw * Icv0)) + (1.0 - ga) * Icv0;
        double wcn    = om * (q * (inv_iw * wcv0)) + (1.0 - om) * wcv0;

        sIc[i1][tid] = icn;
        sWc[i2][tid] = wcn;
        yh_o[step * NFc] = (float)yhat;
        e_o[step * NFc]  = (float)(yt0 - yhat);

        ss = snew; tt = tnew;
        Icv0 = Icv1; Icv1 = Icv2;
        wcv0 = wcv1; wcv1 = wcv2;
        yt0 = yt1; yt1 = yt2; yt2 = yt3; yt3 = yt4;
        i1  = (i1  + 1 == P1c) ? 0 : i1  + 1;
        i2  = (i2  + 1 == P2c) ? 0 : i2  + 1;
        i1p = (i1p + 1 == P1c) ? 0 : i1p + 1;
        i2p = (i2p + 1 == P2c) ? 0 : i2p + 1;
    }

    float* __restrict__ fc_o = out + OFF_FC + (size_t)bb * MAXH * NFc + f;
    {
        int k1 = 8, k2 = 8;
        for (int k = 0; k < MAXH; ++k) {
            double cb = sIc[k1][tid];
            double cc = sWc[k2][tid];
            double ca = ss + (double)(k + 1) * tt;
            fc_o[k * NFc] = (float)(ca * cb * cc);
            k1 = (k1 + 1 == P1c) ? 0 : k1 + 1;
            k2 = (k2 + 1 == P2c) ? 0 : k2 + 1;
        }
    }
    {
        float* __restrict__ ic_o = out + OFF_IC + (size_t)bb * P1c * NFc + f;
        int k1 = 8;
        #pragma unroll
        for (int j = 0; j < P1c; ++j) {
            ic_o[j * NFc] = (float)sIc[k1][tid];
            k1 = (k1 + 1 == P1c) ? 0 : k1 + 1;
        }
    }
    {
        float* __restrict__ wc_o = out + OFF_WC + (size_t)bb * P2c * NFc + f;
        int k2 = 8;
        for (int j = 0; j < P2c; ++j) {
            wc_o[j * NFc] = (float)sWc[k2][tid];
            k2 = (k2 + 1 == P2c) ? 0 : k2 + 1;
        }
    }

    out[OFF_T + bb * NFc + f] = (float)tt;
    out[OFF_S + bb * NFc + f] = (float)ss;
}

extern "C" void kernel_launch(void* const* d_in, const int* in_sizes, int n_in,
                              void* d_out, int out_size, void* d_ws, size_t ws_size,
                              hipStream_t stream)
{
    const float* y      = (const float*)d_in[0];
    const float* alphas = (const float*)d_in[1];
    const float* betas  = (const float*)d_in[2];
    const float* gammas = (const float*)d_in[3];
    const float* omegas = (const float*)d_in[4];
    float* out = (float*)d_out;

    if (ws_size >= WS_NEED) {
        float*  wsy  = (float*)((char*)d_ws + WSO_Y);
        double* wsyh = (double*)((char*)d_ws + WSO_YH);
        double* wsst = (double*)((char*)d_ws + WSO_ST);
        hipLaunchKernelGGL(dshw_transpose, dim3((NSTEP * NSERIES) / 256), dim3(256),
                           0, stream, y, wsy);
        hipLaunchKernelGGL(dshw_scan5, dim3(NSERIES / NT), dim3(NT), 0, stream,
                           wsy, alphas, betas, gammas, omegas, wsyh, wsst, out);
        hipLaunchKernelGGL(dshw_finish, dim3(65 * BSc), dim3(256), 0, stream,
                           wsy, wsyh, wsst, out);
    } else {
        hipLaunchKernelGGL(dshw_fused, dim3(NSERIES / NT), dim3(NT), 0, stream,
                           y, alphas, betas, gammas, omegas, out);
    }
}

// Round 8
// 152.104 us; speedup vs baseline: 1.0471x; 1.0471x over previous
//
#include <hip/hip_runtime.h>
#include <math.h>

// DSHW — R8: R6 scan (best: 86 µs) with the store path ablated.
// Only change vs R6: the two per-step strided f32 stores (yh, e) become ONE
// packed float2 store into ws (values computed identically in-scan ->
// bit-identical outputs); a parallel finish kernel scatters yh/e and emits
// fcast + rolled Ic/wc from the f64 state dump. Launch count unchanged (2).
// This isolates "in-order vmcnt store-retirement" as the suspected pacer of
// the remaining ~400 cyc/step (VALUBusy ~9% on active CUs, 0 conflicts).

#define P1c   24
#define P2c   168
#define NSTEP 512
#define BSc   64
#define NFc   16
#define MAXH  336
#define NT    32
#define NSERIES 1024

#define OFF_FC   0
#define OFF_YH   (BSc * MAXH * NFc)
#define OFF_E    (OFF_YH + BSc * NSTEP * NFc)
#define OFF_IC   (OFF_E  + BSc * NSTEP * NFc)
#define OFF_WC   (OFF_IC + BSc * P1c * NFc)
#define OFF_T    (OFF_WC + BSc * P2c * NFc)
#define OFF_S    (OFF_T  + BSc * NFc)

// ws layout (bytes)
#define WSO_YE   0                                        // float2 [NSTEP][NSERIES]
#define WSO_ST   (WSO_YE + (size_t)NSTEP * NSERIES * 8)   // f64 [194][NSERIES]
#define WS_NEED  (WSO_ST + (size_t)194 * NSERIES * 8)

__device__ __forceinline__ double nrcp(double a) {
    double x = __builtin_amdgcn_rcp(a);          // v_rcp_f64, no VCC
    x = fma(fma(-a, x, 1.0), x, x);
    x = fma(fma(-a, x, 1.0), x, x);              // ~1 ulp
    return x;
}

// ---------------------------------------------------------------------------
// Kernel 1: init + scan (R6 structure; only the store path changed).
// ---------------------------------------------------------------------------
__global__ __launch_bounds__(NT, 1)
void dshw_scan6(const float* __restrict__ y,
                const float* __restrict__ alphas,
                const float* __restrict__ betas,
                const float* __restrict__ gammas,
                const float* __restrict__ omegas,
                float2* __restrict__ wsye,
                double* __restrict__ wsst,
                float* __restrict__ out)
{
    __shared__ double sW[P2c][NT];   // wc only — 42 KiB

    const int tid = threadIdx.x;
    const int g   = blockIdx.x * NT + tid;
    const int bb  = g >> 4;
    const int f   = g & 15;

    const float* __restrict__ yb = y + (size_t)bb * NSTEP * NFc + f;

    const double al = 1.0 / (1.0 + exp(-(double)alphas[f]));
    const double be = 1.0 / (1.0 + exp(-(double)betas[f]));
    const double ga = 1.0 / (1.0 + exp(-(double)gammas[f]));
    const double om = 1.0 / (1.0 + exp(-(double)omegas[f]));
    const double one_m_al = 1.0 - al, one_m_be = 1.0 - be;
    const double one_m_ga = 1.0 - ga, one_m_om = 1.0 - om;

    // ---------------- init (identical to R6) ----------------
    double Icr[P1c];
    double sum48 = 0.0;
    #pragma unroll
    for (int ph = 0; ph < P1c; ++ph) {
        double v0 = (double)yb[ph * NFc];
        double v1 = (double)yb[(ph + P1c) * NFc];
        Icr[ph] = 0.5 * (v0 + v1);
        sum48 += v0 + v1;
    }
    const double inv_mean48 = 48.0 * nrcp(sum48);
    #pragma unroll
    for (int ph = 0; ph < P1c; ++ph) Icr[ph] *= inv_mean48;

    double sa = 0.0, sb = 0.0;
    #pragma unroll 8
    for (int i = 0; i < P2c; ++i) {
        double v0 = (double)yb[i * NFc];
        double v1 = (double)yb[(i + P2c) * NFc];
        sW[i][tid] = 0.5 * (v0 + v1);
        sa += v0; sb += v1;
    }
    const double mean336     = (sa + sb) * (1.0 / 336.0);
    const double inv_mean336 = nrcp(mean336);
    #pragma unroll
    for (int ph = 0; ph < P1c; ++ph) {
        double rI = inv_mean336 * nrcp(Icr[ph]);
        #pragma unroll
        for (int r = 0; r < 7; ++r) {
            const int i = ph + 24 * r;
            sW[i][tid] = sW[i][tid] * rI;
        }
    }

    double tt = 0.5 * ((sa - sb) * (1.0 / (168.0 * 168.0)) +
                       ((double)yb[(P2c - 1) * NFc] - (double)yb[0]) * (1.0 / 168.0));
    double ss = mean336 - 168.5 * tt;

    // ---------------- scan (R6 rings; float2 packed output) ----------------
    double yring[12], wring[24], uring[8], iwring[6], snring[3];

    #pragma unroll
    for (int k = 0; k < 12; ++k) yring[k] = (double)yb[k * NFc];
    #pragma unroll
    for (int k = 0; k < 12; ++k) wring[k] = sW[k][tid];
    // B warmup: steps 0..3
    #pragma unroll
    for (int m = 0; m < 4; ++m) {
        double iw  = Icr[m] * wring[m];
        double inv = nrcp(iw);
        iwring[m % 6] = iw;
        uring[m % 8]  = yring[m % 12] * inv;
    }

    int i2r = 12;   // LDS read phase (s+12) % 168
    int i2w = 0;    // LDS write phase (s-2) % 168

    // ---- group 0 (s0 = 0): D guarded for j < 2 ----
    #pragma unroll
    for (int j = 0; j < 24; ++j) {
        const int s = j;
        // C
        double yv   = yring[j % 12];
        double spt  = ss + tt;
        double yhat = spt * iwring[j % 6];
        double snew = al * uring[j % 8] + one_m_al * spt;
        double tnew = be * (snew - ss) + one_m_be * tt;
        wsye[(size_t)s * NSERIES + g] = make_float2((float)yhat, (float)(yv - yhat));
        snring[j % 3] = snew;
        ss = snew; tt = tnew;
        // A
        wring[(j + 12) % 24] = sW[i2r][tid];
        i2r = (i2r + 1 == P2c) ? 0 : i2r + 1;
        yring[j % 12] = (double)yb[(s + 12) * NFc];
        // B (step s+4)
        {
            double iw2  = Icr[(j + 4) % 24] * wring[(j + 4) % 24];
            double inv2 = nrcp(iw2);
            iwring[(j + 4) % 6] = iw2;
            uring[(j + 4) % 8]  = yring[(j + 4) % 12] * inv2;
        }
        // D (step s-2)
        if (j >= 2) {
            double r   = nrcp(snring[(j + 1) % 3]);
            double uDr = uring[(j + 6) % 8] * r;
            double icO = Icr[(j + 22) % 24];
            double wcO = wring[(j + 22) % 24];
            Icr[(j + 22) % 24] = icO * fma(ga, uDr, one_m_ga);
            sW[i2w][tid] = wcO * fma(om, uDr, one_m_om);
            i2w = (i2w + 1 == P2c) ? 0 : i2w + 1;
        }
    }

    // ---- steady groups: s0 = 24..480 ----
    for (int s0 = 24; s0 <= 480; s0 += 24) {
        #pragma unroll
        for (int j = 0; j < 24; ++j) {
            const int s = s0 + j;
            // C
            double yv   = yring[j % 12];
            double spt  = ss + tt;
            double yhat = spt * iwring[j % 6];
            double snew = al * uring[j % 8] + one_m_al * spt;
            double tnew = be * (snew - ss) + one_m_be * tt;
            wsye[(size_t)s * NSERIES + g] = make_float2((float)yhat, (float)(yv - yhat));
            snring[j % 3] = snew;
            ss = snew; tt = tnew;
            // A
            wring[(j + 12) % 24] = sW[i2r][tid];
            i2r = (i2r + 1 == P2c) ? 0 : i2r + 1;
            int pidx = s + 12; pidx = (pidx < NSTEP) ? pidx : (NSTEP - 1);
            yring[j % 12] = (double)yb[pidx * NFc];
            // B (step s+4)
            {
                double iw2  = Icr[(j + 4) % 24] * wring[(j + 4) % 24];
                double inv2 = nrcp(iw2);
                iwring[(j + 4) % 6] = iw2;
                uring[(j + 4) % 8]  = yring[(j + 4) % 12] * inv2;
            }
            // D (step s-2)
            {
                double r   = nrcp(snring[(j + 1) % 3]);
                double uDr = uring[(j + 6) % 8] * r;
                double icO = Icr[(j + 22) % 24];
                double wcO = wring[(j + 22) % 24];
                Icr[(j + 22) % 24] = icO * fma(ga, uDr, one_m_ga);
                sW[i2w][tid] = wcO * fma(om, uDr, one_m_om);
                i2w = (i2w + 1 == P2c) ? 0 : i2w + 1;
            }
        }
    }

    // ---- tail: steps 504..511 ----
    #pragma unroll
    for (int j = 0; j < 8; ++j) {
        const int s = 504 + j;
        double yv   = yring[j % 12];
        double spt  = ss + tt;
        double yhat = spt * iwring[j % 6];
        double snew = al * uring[j % 8] + one_m_al * spt;
        double tnew = be * (snew - ss) + one_m_be * tt;
        wsye[(size_t)s * NSERIES + g] = make_float2((float)yhat, (float)(yv - yhat));
        snring[j % 3] = snew;
        ss = snew; tt = tnew;
        if (j < 4) {   // B for steps 508..511
            double iw2  = Icr[(j + 4) % 24] * wring[(j + 4) % 24];
            double inv2 = nrcp(iw2);
            iwring[(j + 4) % 6] = iw2;
            uring[(j + 4) % 8]  = yring[(j + 4) % 12] * inv2;
        }
        {   // D for steps 502..509
            double r   = nrcp(snring[(j + 1) % 3]);
            double uDr = uring[(j + 6) % 8] * r;
            double icO = Icr[(j + 22) % 24];
            double wcO = wring[(j + 22) % 24];
            Icr[(j + 22) % 24] = icO * fma(ga, uDr, one_m_ga);
            sW[i2w][tid] = wcO * fma(om, uDr, one_m_om);
            i2w = (i2w + 1 == P2c) ? 0 : i2w + 1;
        }
    }
    // drain D: steps 510, 511
    {
        double r   = nrcp(snring[0]);
        double uDr = uring[6] * r;
        double icO = Icr[6], wcO = wring[6];
        Icr[6] = icO * fma(ga, uDr, one_m_ga);
        sW[i2w][tid] = wcO * fma(om, uDr, one_m_om);
        i2w = (i2w + 1 == P2c) ? 0 : i2w + 1;
    }
    {
        double r   = nrcp(snring[1]);
        double uDr = uring[7] * r;
        double icO = Icr[7], wcO = wring[7];
        Icr[7] = icO * fma(ga, uDr, one_m_ga);
        sW[i2w][tid] = wcO * fma(om, uDr, one_m_om);
    }

    // dump raw f64 state, item-major (coalesced)
    #pragma unroll
    for (int p = 0; p < P1c; ++p)  wsst[(size_t)p * NSERIES + g] = Icr[p];
    #pragma unroll 8
    for (int p = 0; p < P2c; ++p)  wsst[(size_t)(P1c + p) * NSERIES + g] = sW[p][tid];
    wsst[(size_t)192 * NSERIES + g] = ss;
    wsst[(size_t)193 * NSERIES + g] = tt;

    out[OFF_T + bb * NFc + f] = (float)tt;
    out[OFF_S + bb * NFc + f] = (float)ss;
}

// ---------------------------------------------------------------------------
// Kernel 2: finish — scatter yh/e + fcast + rolled Ic/wc.
// items: 0..511 yh/e (n), 512..847 fcast (k), 848..871 Ic, 872..1039 wc.
// ---------------------------------------------------------------------------
__global__ __launch_bounds__(256)
void dshw_finish(const float2* __restrict__ wsye,
                 const double* __restrict__ wsst,
                 float* __restrict__ out)
{
    const int f      = threadIdx.x & 15;
    const int isub   = threadIdx.x >> 4;
    const int bb     = blockIdx.x & 63;
    const int chunk  = blockIdx.x >> 6;       // 0..64
    const int item   = chunk * 16 + isub;     // 0..1039
    const int series = bb * NFc + f;

    if (item < NSTEP) {
        const int n = item;
        float2 ye = wsye[(size_t)n * NSERIES + series];
        out[OFF_YH + (bb * NSTEP + n) * NFc + f] = ye.x;
        out[OFF_E  + (bb * NSTEP + n) * NFc + f] = ye.y;
    } else if (item < NSTEP + MAXH) {
        const int k = item - NSTEP;
        double cb = wsst[(size_t)((k + 8) % P1c) * NSERIES + series];
        double cc = wsst[(size_t)(P1c + (k + 8) % P2c) * NSERIES + series];
        double ssv = wsst[(size_t)192 * NSERIES + series];
        double ttv = wsst[(size_t)193 * NSERIES + series];
        double ca = ssv + (double)(k + 1) * ttv;
        out[OFF_FC + (bb * MAXH + k) * NFc + f] = (float)(ca * cb * cc);
    } else if (item < NSTEP + MAXH + P1c) {
        const int j = item - (NSTEP + MAXH);
        out[OFF_IC + (bb * P1c + j) * NFc + f] =
            (float)wsst[(size_t)((j + 8) % P1c) * NSERIES + series];
    } else if (item < NSTEP + MAXH + P1c + P2c) {
        const int j = item - (NSTEP + MAXH + P1c);
        out[OFF_WC + (bb * P2c + j) * NFc + f] =
            (float)wsst[(size_t)(P1c + (j + 8) % P2c) * NSERIES + series];
    }
}

// ---------------------------------------------------------------------------
// Fallback (R2 fused kernel, verbatim) — used only if ws is too small.
// ---------------------------------------------------------------------------
__global__ __launch_bounds__(NT, 1)
void dshw_fused(const float* __restrict__ y,
                const float* __restrict__ alphas,
                const float* __restrict__ betas,
                const float* __restrict__ gammas,
                const float* __restrict__ omegas,
                float* __restrict__ out)
{
    __shared__ double sIc[P1c][NT];
    __shared__ double sWc[P2c][NT];

    const int tid = threadIdx.x;
    const int g   = blockIdx.x * NT + tid;
    const int bb  = g >> 4;
    const int f   = g & 15;

    const float* __restrict__ yb = y + (size_t)bb * NSTEP * NFc + f;

    const double al = 1.0 / (1.0 + exp(-(double)alphas[f]));
    const double be = 1.0 / (1.0 + exp(-(double)betas[f]));
    const double ga = 1.0 / (1.0 + exp(-(double)gammas[f]));
    const double om = 1.0 / (1.0 + exp(-(double)omegas[f]));

    double sum48 = 0.0;
    #pragma unroll
    for (int ph = 0; ph < P1c; ++ph) {
        double v0 = (double)yb[ph * NFc];
        double v1 = (double)yb[(ph + P1c) * NFc];
        sIc[ph][tid] = 0.5 * (v0 + v1);
        sum48 += v0 + v1;
    }
    const double inv_mean48 = 48.0 / sum48;
    #pragma unroll
    for (int ph = 0; ph < P1c; ++ph) sIc[ph][tid] *= inv_mean48;

    double sum168a = 0.0, sum168b = 0.0;
    for (int i = 0; i < P2c; ++i) {
        double v0 = (double)yb[i * NFc];
        double v1 = (double)yb[(i + P2c) * NFc];
        sWc[i][tid] = 0.5 * (v0 + v1);
        sum168a += v0;
        sum168b += v1;
    }
    const double mean336 = (sum168a + sum168b) * (1.0 / 336.0);
    for (int i = 0; i < P2c; ++i) {
        sWc[i][tid] = (sWc[i][tid] / mean336) / sIc[i % P1c][tid];
    }

    double tt = 0.5 * ((sum168a - sum168b) * (1.0 / (168.0 * 168.0)) +
                       ((double)yb[(P2c - 1) * NFc] - (double)yb[0]) * (1.0 / 168.0));
    double ss = mean336 - 168.5 * tt;

    float* __restrict__ yh_o = out + OFF_YH + (size_t)bb * NSTEP * NFc + f;
    float* __restrict__ e_o  = out + OFF_E  + (size_t)bb * NSTEP * NFc + f;

    int i1 = 0, i2 = 0;
    int i1p = 2, i2p = 2;

    double Icv0 = sIc[0][tid], Icv1 = sIc[1][tid];
    double wcv0 = sWc[0][tid], wcv1 = sWc[1][tid];
    double yt0 = (double)yb[0 * NFc], yt1 = (double)yb[1 * NFc];
    double yt2 = (double)yb[2 * NFc], yt3 = (double)yb[3 * NFc];

    #pragma unroll 4
    for (int step = 0; step < NSTEP; ++step) {
        double Icv2 = sIc[i1p][tid];
        double wcv2 = sWc[i2p][tid];
        int    pidx = step + 4; pidx = (pidx < NSTEP) ? pidx : (NSTEP - 1);
        double yt4  = (double)yb[pidx * NFc];

        double iw     = Icv0 * wcv0;
        double spt    = ss + tt;
        double yhat   = spt * iw;
        double inv_iw = 1.0 / iw;
        double u      = yt0 * inv_iw;
        double snew   = al * u + (1.0 - al) * spt;
        double tnew   = be * (snew - ss) + (1.0 - be) * tt;
        double q      = yt0 / snew;
        double icn    = ga * (q * (inv_iw * Icv0)) + (1.0 - ga) * Icv0;
        double wcn    = om * (q * (inv_iw * wcv0)) + (1.0 - om) * wcv0;

        sIc[i1][tid] = icn;
        sWc[i2][tid] = wcn;
        yh_o[step * NFc] = (float)yhat;
        e_o[step * NFc]  = (float)(yt0 - yhat);

        ss = snew; tt = tnew;
        Icv0 = Icv1; Icv1 = Icv2;
        wcv0 = wcv1; wcv1 = wcv2;
        yt0 = yt1; yt1 = yt2; yt2 = yt3; yt3 = yt4;
        i1  = (i1  + 1 == P1c) ? 0 : i1  + 1;
        i2  = (i2  + 1 == P2c) ? 0 : i2  + 1;
        i1p = (i1p + 1 == P1c) ? 0 : i1p + 1;
        i2p = (i2p + 1 == P2c) ? 0 : i2p + 1;
    }

    float* __restrict__ fc_o = out + OFF_FC + (size_t)bb * MAXH * NFc + f;
    {
        int k1 = 8, k2 = 8;
        for (int k = 0; k < MAXH; ++k) {
            double cb = sIc[k1][tid];
            double cc = sWc[k2][tid];
            double ca = ss + (double)(k + 1) * tt;
            fc_o[k * NFc] = (float)(ca * cb * cc);
            k1 = (k1 + 1 == P1c) ? 0 : k1 + 1;
            k2 = (k2 + 1 == P2c) ? 0 : k2 + 1;
        }
    }
    {
        float* __restrict__ ic_o = out + OFF_IC + (size_t)bb * P1c * NFc + f;
        int k1 = 8;
        #pragma unroll
        for (int j = 0; j < P1c; ++j) {
            ic_o[j * NFc] = (float)sIc[k1][tid];
            k1 = (k1 + 1 == P1c) ? 0 : k1 + 1;
        }
    }
    {
        float* __restrict__ wc_o = out + OFF_WC + (size_t)bb * P2c * NFc + f;
        int k2 = 8;
        for (int j = 0; j < P2c; ++j) {
            wc_o[j * NFc] = (float)sWc[k2][tid];
            k2 = (k2 + 1 == P2c) ? 0 : k2 + 1;
        }
    }

    out[OFF_T + bb * NFc + f] = (float)tt;
    out[OFF_S + bb * NFc + f] = (float)ss;
}

extern "C" void kernel_launch(void* const* d_in, const int* in_sizes, int n_in,
                              void* d_out, int out_size, void* d_ws, size_t ws_size,
                              hipStream_t stream)
{
    const float* y      = (const float*)d_in[0];
    const float* alphas = (const float*)d_in[1];
    const float* betas  = (const float*)d_in[2];
    const float* gammas = (const float*)d_in[3];
    const float* omegas = (const float*)d_in[4];
    float* out = (float*)d_out;

    if (ws_size >= WS_NEED) {
        float2* wsye = (float2*)((char*)d_ws + WSO_YE);
        double* wsst = (double*)((char*)d_ws + WSO_ST);
        hipLaunchKernelGGL(dshw_scan6, dim3(NSERIES / NT), dim3(NT), 0, stream,
                           y, alphas, betas, gammas, omegas, wsye, wsst, out);
        hipLaunchKernelGGL(dshw_finish, dim3(65 * BSc), dim3(256), 0, stream,
                           wsye, wsst, out);
    } else {
        hipLaunchKernelGGL(dshw_fused, dim3(NSERIES / NT), dim3(NT), 0, stream,
                           y, alphas, betas, gammas, omegas, out);
    }
}

// Round 9
// 150.620 us; speedup vs baseline: 1.0574x; 1.0099x over previous
//
#include <hip/hip_runtime.h>
#include <math.h>

// DSHW — R9: 3-wave specialized pipeline (B: reciprocal#1/u, C: serial chain,
// D: reciprocal#2/state-update), 8-step windows, barrier-synced LDS rings.
// All f64 expressions textually identical to R6/R8 -> bit-identical outputs.
// Ring disjointness per window (proofs in session journal):
//   rU  (u, mod 24): B writes [b,b+7], C reads [b-8,b-1], D reads [b-16,b-9]
//   rIw (iw, mod 16): B writes one half, C reads the other
//   rS  (snew, mod 16): C writes one half, D reads the other
//   rIc (Ic state, mod 24): D RMWs [b-16..], B reads [b..] — diff 16, disjoint
//   sWc (wc state, 168): D writes [b-16..], B reads [b..] — diff 16, disjoint

#define P1c   24
#define P2c   168
#define NSTEP 512
#define BSc   64
#define NFc   16
#define MAXH  336
#define NL    32
#define NSERIES 1024

#define OFF_FC   0
#define OFF_YH   (BSc * MAXH * NFc)
#define OFF_E    (OFF_YH + BSc * NSTEP * NFc)
#define OFF_IC   (OFF_E  + BSc * NSTEP * NFc)
#define OFF_WC   (OFF_IC + BSc * P1c * NFc)
#define OFF_T    (OFF_WC + BSc * P2c * NFc)
#define OFF_S    (OFF_T  + BSc * NFc)

// ws layout (bytes)
#define WSO_YE   0                                        // float2 [NSTEP][NSERIES]
#define WSO_ST   (WSO_YE + (size_t)NSTEP * NSERIES * 8)   // f64 [194][NSERIES]
#define WS_NEED  (WSO_ST + (size_t)194 * NSERIES * 8)

__device__ __forceinline__ double nrcp(double a) {
    double x = __builtin_amdgcn_rcp(a);          // v_rcp_f64, no VCC
    x = fma(fma(-a, x, 1.0), x, x);
    x = fma(fma(-a, x, 1.0), x, x);              // ~1 ulp
    return x;
}

// ---------------------------------------------------------------------------
// Kernel 1: 3-wave pipelined scan. Block = 192 threads (3 waves); lanes 32-63
// of each wave duplicate lanes 0-31 (same series, same LDS columns, same
// values — global stores predicated to lane<32).
// ---------------------------------------------------------------------------
__global__ __launch_bounds__(192, 1)
void dshw_scan7(const float* __restrict__ y,
                const float* __restrict__ alphas,
                const float* __restrict__ betas,
                const float* __restrict__ gammas,
                const float* __restrict__ omegas,
                float2* __restrict__ wsye,
                double* __restrict__ wsst,
                float* __restrict__ out)
{
    __shared__ double sWc[P2c][NL];   // 43008 B  wc seasonal state
    __shared__ double rIc[P1c][NL];   //  6144 B  Ic state ring (slot = phase)
    __shared__ double rU [24][NL];    //  6144 B  u ring   (slot = s%24)
    __shared__ double rIw[16][NL];    //  4096 B  iw ring  (slot = s%16)
    __shared__ double rS [16][NL];    //  4096 B  snew ring(slot = s%16)
                                      // total 63488 B

    const int tid  = threadIdx.x;
    const int wave = tid >> 6;        // 0=B, 1=C, 2=D
    const int lane = tid & 63;
    const int ln   = lane & 31;
    const int g    = blockIdx.x * NL + ln;
    const int bb   = g >> 4;
    const int f    = g & 15;
    const float* __restrict__ yb = y + (size_t)bb * NSTEP * NFc + f;

    const double al = 1.0 / (1.0 + exp(-(double)alphas[f]));
    const double be = 1.0 / (1.0 + exp(-(double)betas[f]));
    const double ga = 1.0 / (1.0 + exp(-(double)gammas[f]));
    const double om = 1.0 / (1.0 + exp(-(double)omegas[f]));
    const double one_m_al = 1.0 - al, one_m_be = 1.0 - be;
    const double one_m_ga = 1.0 - ga, one_m_om = 1.0 - om;

    // ---------------- init (wave B; expressions verbatim R8) ----------------
    if (wave == 0) {
        double Icr[P1c];
        double sum48 = 0.0;
        #pragma unroll
        for (int ph = 0; ph < P1c; ++ph) {
            double v0 = (double)yb[ph * NFc];
            double v1 = (double)yb[(ph + P1c) * NFc];
            Icr[ph] = 0.5 * (v0 + v1);
            sum48 += v0 + v1;
        }
        const double inv_mean48 = 48.0 * nrcp(sum48);
        #pragma unroll
        for (int ph = 0; ph < P1c; ++ph) { Icr[ph] *= inv_mean48; rIc[ph][ln] = Icr[ph]; }

        double sa = 0.0, sb = 0.0;
        #pragma unroll 8
        for (int i = 0; i < P2c; ++i) {
            double v0 = (double)yb[i * NFc];
            double v1 = (double)yb[(i + P2c) * NFc];
            sWc[i][ln] = 0.5 * (v0 + v1);
            sa += v0; sb += v1;
        }
        const double mean336     = (sa + sb) * (1.0 / 336.0);
        const double inv_mean336 = nrcp(mean336);
        #pragma unroll
        for (int ph = 0; ph < P1c; ++ph) {
            double rI = inv_mean336 * nrcp(Icr[ph]);
            #pragma unroll
            for (int r = 0; r < 7; ++r) {
                const int i = ph + 24 * r;
                sWc[i][ln] = sWc[i][ln] * rI;
            }
        }
        double tt0 = 0.5 * ((sa - sb) * (1.0 / (168.0 * 168.0)) +
                            ((double)yb[(P2c - 1) * NFc] - (double)yb[0]) * (1.0 / 168.0));
        double ss0 = mean336 - 168.5 * tt0;
        rIw[8][ln] = ss0;          // handoff to C (B's window-0 writes touch 0..7)
        rIw[9][ln] = tt0;
    }
    __syncthreads();

    // ---------------- per-wave state & preloads ----------------
    float  yA[8], yB_[8];
    double ss = 0.0, tt = 0.0;
    int p168b = 0, icb = 0, ub = 0;   // wave B bases
    int cu = 0;                       // wave C rU base
    int du = 0, dic = 0, p168d = 0;   // wave D bases

    if (wave == 0) {
        #pragma unroll
        for (int j = 0; j < 8; ++j) yA[j] = yb[j * NFc];
    } else if (wave == 1) {
        #pragma unroll
        for (int j = 0; j < 8; ++j) yA[j] = yb[j * NFc];
        ss = rIw[8][ln];
        tt = rIw[9][ln];
    }

    // ---------------- window bodies ----------------
#define B_WIN(IWB, YUSE, YFILL, W)                                             \
    {                                                                          \
        _Pragma("unroll")                                                      \
        for (int j = 0; j < 8; ++j) {                                          \
            double Ic  = rIc[icb + j][ln];                                     \
            double wc  = sWc[p168b + j][ln];                                   \
            double iw  = Ic * wc;                                              \
            double inv = nrcp(iw);                                             \
            double u   = (double)YUSE[j] * inv;                                \
            rU[ub + j][ln]    = u;                                             \
            rIw[(IWB) + j][ln] = iw;                                           \
            int pidx = (W) * 8 + 8 + j; pidx = (pidx > 511) ? 511 : pidx;      \
            YFILL[j] = yb[pidx * NFc];                                         \
        }                                                                      \
        icb += 8; if (icb >= 24) icb -= 24;                                    \
        ub  += 8; if (ub  >= 24) ub  -= 24;                                    \
        p168b += 8; if (p168b >= P2c) p168b -= P2c;                            \
    }

#define C_WIN(CB, YUSE, YFILL, W, DOFILL)                                      \
    {                                                                          \
        _Pragma("unroll")                                                      \
        for (int j = 0; j < 8; ++j) {                                          \
            double iw   = rIw[(CB) + j][ln];                                   \
            double u    = rU[cu + j][ln];                                      \
            double spt  = ss + tt;                                             \
            double yhat = spt * iw;                                            \
            double snew = al * u + one_m_al * spt;                             \
            double tnew = be * (snew - ss) + one_m_be * tt;                    \
            rS[(CB) + j][ln] = snew;                                           \
            double yv = (double)YUSE[j];                                       \
            if (lane < 32)                                                     \
                wsye[(size_t)(((W) - 1) * 8 + j) * NSERIES + g] =              \
                    make_float2((float)yhat, (float)(yv - yhat));              \
            ss = snew; tt = tnew;                                              \
        }                                                                      \
        if (DOFILL) {                                                          \
            _Pragma("unroll")                                                  \
            for (int j = 0; j < 8; ++j) YFILL[j] = yb[((W) * 8 + j) * NFc];    \
        }                                                                      \
        cu += 8; if (cu >= 24) cu -= 24;                                       \
    }

#define D_WIN(DB)                                                              \
    {                                                                          \
        _Pragma("unroll")                                                      \
        for (int j = 0; j < 8; ++j) {                                          \
            double snew = rS[(DB) + j][ln];                                    \
            double u    = rU[du + j][ln];                                      \
            double r    = nrcp(snew);                                          \
            double uDr  = u * r;                                               \
            double Ico  = rIc[dic + j][ln];                                    \
            double wco  = sWc[p168d + j][ln];                                  \
            rIc[dic + j][ln]   = Ico * fma(ga, uDr, one_m_ga);                 \
            sWc[p168d + j][ln] = wco * fma(om, uDr, one_m_om);                 \
        }                                                                      \
        du  += 8; if (du  >= 24) du  -= 24;                                    \
        dic += 8; if (dic >= 24) dic -= 24;                                    \
        p168d += 8; if (p168d >= P2c) p168d -= P2c;                            \
    }

    // ---------------- windowed pipeline: 66 windows, unrolled by 2 ----------
    for (int wp = 0; wp < 33; ++wp) {
        const int w0 = 2 * wp;        // even window
        const int w1 = 2 * wp + 1;    // odd window
        // even: B uses yA fills yB_ (IWB=0); C uses yB_ fills yA (base 8); D base 0
        if (wave == 0)      { if (w0 <= 63)            B_WIN(0, yA, yB_, w0); }
        else if (wave == 1) { if (w0 >= 1 && w0 <= 64) C_WIN(8, yB_, yA, w0, (w0 <= 63)); }
        else                { if (w0 >= 2)             D_WIN(0); }
        __syncthreads();
        // odd: B uses yB_ fills yA (IWB=8); C uses yA fills yB_ (base 0); D base 8
        if (wave == 0)      { if (w1 <= 63)            B_WIN(8, yB_, yA, w1); }
        else if (wave == 1) { if (w1 <= 64)            C_WIN(0, yA, yB_, w1, (w1 <= 63)); }
        else                { if (w1 >= 2 && w1 <= 65) D_WIN(8); }
        __syncthreads();
    }

    // ---------------- dumps ----------------
    if (wave == 1 && lane < 32) {
        out[OFF_T + bb * NFc + f] = (float)tt;
        out[OFF_S + bb * NFc + f] = (float)ss;
        wsst[(size_t)192 * NSERIES + g] = ss;
        wsst[(size_t)193 * NSERIES + g] = tt;
    }
    if (wave == 2 && lane < 32) {
        #pragma unroll
        for (int p = 0; p < P1c; ++p)
            wsst[(size_t)p * NSERIES + g] = rIc[p][ln];   // slot index == phase
        #pragma unroll 8
        for (int p = 0; p < P2c; ++p)
            wsst[(size_t)(P1c + p) * NSERIES + g] = sWc[p][ln];
    }
#undef B_WIN
#undef C_WIN
#undef D_WIN
}

// ---------------------------------------------------------------------------
// Kernel 2: finish — scatter yh/e + fcast + rolled Ic/wc (verbatim R8).
// ---------------------------------------------------------------------------
__global__ __launch_bounds__(256)
void dshw_finish(const float2* __restrict__ wsye,
                 const double* __restrict__ wsst,
                 float* __restrict__ out)
{
    const int f      = threadIdx.x & 15;
    const int isub   = threadIdx.x >> 4;
    const int bb     = blockIdx.x & 63;
    const int chunk  = blockIdx.x >> 6;       // 0..64
    const int item   = chunk * 16 + isub;     // 0..1039
    const int series = bb * NFc + f;

    if (item < NSTEP) {
        const int n = item;
        float2 ye = wsye[(size_t)n * NSERIES + series];
        out[OFF_YH + (bb * NSTEP + n) * NFc + f] = ye.x;
        out[OFF_E  + (bb * NSTEP + n) * NFc + f] = ye.y;
    } else if (item < NSTEP + MAXH) {
        const int k = item - NSTEP;
        double cb = wsst[(size_t)((k + 8) % P1c) * NSERIES + series];
        double cc = wsst[(size_t)(P1c + (k + 8) % P2c) * NSERIES + series];
        double ssv = wsst[(size_t)192 * NSERIES + series];
        double ttv = wsst[(size_t)193 * NSERIES + series];
        double ca = ssv + (double)(k + 1) * ttv;
        out[OFF_FC + (bb * MAXH + k) * NFc + f] = (float)(ca * cb * cc);
    } else if (item < NSTEP + MAXH + P1c) {
        const int j = item - (NSTEP + MAXH);
        out[OFF_IC + (bb * P1c + j) * NFc + f] =
            (float)wsst[(size_t)((j + 8) % P1c) * NSERIES + series];
    } else if (item < NSTEP + MAXH + P1c + P2c) {
        const int j = item - (NSTEP + MAXH + P1c);
        out[OFF_WC + (bb * P2c + j) * NFc + f] =
            (float)wsst[(size_t)(P1c + (j + 8) % P2c) * NSERIES + series];
    }
}

// ---------------------------------------------------------------------------
// Fallback (R2 fused kernel, verbatim) — used only if ws is too small.
// ---------------------------------------------------------------------------
__global__ __launch_bounds__(32, 1)
void dshw_fused(const float* __restrict__ y,
                const float* __restrict__ alphas,
                const float* __restrict__ betas,
                const float* __restrict__ gammas,
                const float* __restrict__ omegas,
                float* __restrict__ out)
{
    __shared__ double sIc[P1c][32];
    __shared__ double sWc[P2c][32];

    const int tid = threadIdx.x;
    const int g   = blockIdx.x * 32 + tid;
    const int bb  = g >> 4;
    const int f   = g & 15;

    const float* __restrict__ yb = y + (size_t)bb * NSTEP * NFc + f;

    const double al = 1.0 / (1.0 + exp(-(double)alphas[f]));
    const double be = 1.0 / (1.0 + exp(-(double)betas[f]));
    const double ga = 1.0 / (1.0 + exp(-(double)gammas[f]));
    const double om = 1.0 / (1.0 + exp(-(double)omegas[f]));

    double sum48 = 0.0;
    #pragma unroll
    for (int ph = 0; ph < P1c; ++ph) {
        double v0 = (double)yb[ph * NFc];
        double v1 = (double)yb[(ph + P1c) * NFc];
        sIc[ph][tid] = 0.5 * (v0 + v1);
        sum48 += v0 + v1;
    }
    const double inv_mean48 = 48.0 / sum48;
    #pragma unroll
    for (int ph = 0; ph < P1c; ++ph) sIc[ph][tid] *= inv_mean48;

    double sum168a = 0.0, sum168b = 0.0;
    for (int i = 0; i < P2c; ++i) {
        double v0 = (double)yb[i * NFc];
        double v1 = (double)yb[(i + P2c) * NFc];
        sWc[i][tid] = 0.5 * (v0 + v1);
        sum168a += v0;
        sum168b += v1;
    }
    const double mean336 = (sum168a + sum168b) * (1.0 / 336.0);
    for (int i = 0; i < P2c; ++i) {
        sWc[i][tid] = (sWc[i][tid] / mean336) / sIc[i % P1c][tid];
    }

    double tt = 0.5 * ((sum168a - sum168b) * (1.0 / (168.0 * 168.0)) +
                       ((double)yb[(P2c - 1) * NFc] - (double)yb[0]) * (1.0 / 168.0));
    double ss = mean336 - 168.5 * tt;

    float* __restrict__ yh_o = out + OFF_YH + (size_t)bb * NSTEP * NFc + f;
    float* __restrict__ e_o  = out + OFF_E  + (size_t)bb * NSTEP * NFc + f;

    int i1 = 0, i2 = 0;
    int i1p = 2, i2p = 2;

    double Icv0 = sIc[0][tid], Icv1 = sIc[1][tid];
    double wcv0 = sWc[0][tid], wcv1 = sWc[1][tid];
    double yt0 = (double)yb[0 * NFc], yt1 = (double)yb[1 * NFc];
    double yt2 = (double)yb[2 * NFc], yt3 = (double)yb[3 * NFc];

    #pragma unroll 4
    for (int step = 0; step < NSTEP; ++step) {
        double Icv2 = sIc[i1p][tid];
        double wcv2 = sWc[i2p][tid];
        int    pidx = step + 4; pidx = (pidx < NSTEP) ? pidx : (NSTEP - 1);
        double yt4  = (double)yb[pidx * NFc];

        double iw     = Icv0 * wcv0;
        double spt    = ss + tt;
        double yhat   = spt * iw;
        double inv_iw = 1.0 / iw;
        double u      = yt0 * inv_iw;
        double snew   = al * u + (1.0 - al) * spt;
        double tnew   = be * (snew - ss) + (1.0 - be) * tt;
        double q      = yt0 / snew;
        double icn    = ga * (q * (inv_iw * Icv0)) + (1.0 - ga) * Icv0;
        double wcn    = om * (q * (inv_iw * wcv0)) + (1.0 - om) * wcv0;

        sIc[i1][tid] = icn;
        sWc[i2][tid] = wcn;
        yh_o[step * NFc] = (float)yhat;
        e_o[step * NFc]  = (float)(yt0 - yhat);

        ss = snew; tt = tnew;
        Icv0 = Icv1; Icv1 = Icv2;
        wcv0 = wcv1; wcv1 = wcv2;
        yt0 = yt1; yt1 = yt2; yt2 = yt3; yt3 = yt4;
        i1  = (i1  + 1 == P1c) ? 0 : i1  + 1;
        i2  = (i2  + 1 == P2c) ? 0 : i2  + 1;
        i1p = (i1p + 1 == P1c) ? 0 : i1p + 1;
        i2p = (i2p + 1 == P2c) ? 0 : i2p + 1;
    }

    float* __restrict__ fc_o = out + OFF_FC + (size_t)bb * MAXH * NFc + f;
    {
        int k1 = 8, k2 = 8;
        for (int k = 0; k < MAXH; ++k) {
            double cb = sIc[k1][tid];
            double cc = sWc[k2][tid];
            double ca = ss + (double)(k + 1) * tt;
            fc_o[k * NFc] = (float)(ca * cb * cc);
            k1 = (k1 + 1 == P1c) ? 0 : k1 + 1;
            k2 = (k2 + 1 == P2c) ? 0 : k2 + 1;
        }
    }
    {
        float* __restrict__ ic_o = out + OFF_IC + (size_t)bb * P1c * NFc + f;
        int k1 = 8;
        #pragma unroll
        for (int j = 0; j < P1c; ++j) {
            ic_o[j * NFc] = (float)sIc[k1][tid];
            k1 = (k1 + 1 == P1c) ? 0 : k1 + 1;
        }
    }
    {
        float* __restrict__ wc_o = out + OFF_WC + (size_t)bb * P2c * NFc + f;
        int k2 = 8;
        for (int j = 0; j < P2c; ++j) {
            wc_o[j * NFc] = (float)sWc[k2][tid];
            k2 = (k2 + 1 == P2c) ? 0 : k2 + 1;
        }
    }

    out[OFF_T + bb * NFc + f] = (float)tt;
    out[OFF_S + bb * NFc + f] = (float)ss;
}

extern "C" void kernel_launch(void* const* d_in, const int* in_sizes, int n_in,
                              void* d_out, int out_size, void* d_ws, size_t ws_size,
                              hipStream_t stream)
{
    const float* y      = (const float*)d_in[0];
    const float* alphas = (const float*)d_in[1];
    const float* betas  = (const float*)d_in[2];
    const float* gammas = (const float*)d_in[3];
    const float* omegas = (const float*)d_in[4];
    float* out = (float*)d_out;

    if (ws_size >= WS_NEED) {
        float2* wsye = (float2*)((char*)d_ws + WSO_YE);
        double* wsst = (double*)((char*)d_ws + WSO_ST);
        hipLaunchKernelGGL(dshw_scan7, dim3(NSERIES / NL), dim3(192), 0, stream,
                           y, alphas, betas, gammas, omegas, wsye, wsst, out);
        hipLaunchKernelGGL(dshw_finish, dim3(65 * BSc), dim3(256), 0, stream,
                           wsye, wsst, out);
    } else {
        hipLaunchKernelGGL(dshw_fused, dim3(NSERIES / 32), dim3(32), 0, stream,
                           y, alphas, betas, gammas, omegas, out);
    }
}